// Round 5
// baseline (441.024 us; speedup 1.0000x reference)
//
#include <hip/hip_runtime.h>

// GraphNetworkLayer: B=8, N=4096, E=16384, G=64, D=128, fp32 in/out.
// Round 5: occupancy + gather-CSR everywhere.
//  - edge/node MFMA: 16 rows x 64 cols per wave (acc=16 VGPR),
//    __launch_bounds__(256,8) -> target VGPR<=64 -> 8 waves/SIMD.
//  - nodes/glob pre-cast to bf16 (halves gather bytes, no pack in hot loop).
//  - group-CSR (egi/ngi) built with int atomics; agg_resid gathers each
//    (b,g)'s rows once: computes eagg/nagg AND fuses residual in-place.
//  - order: edge_mfma -> adj_gather -> agg_resid(e) -> node_mfma ->
//    agg_resid(n) -> global_block. No float atomics anywhere.

#define DD 128
typedef unsigned short u16;
typedef __attribute__((ext_vector_type(8))) short short8;   // 8 bf16
typedef __attribute__((ext_vector_type(4))) float f32x4;

constexpr int B_ = 8, N_ = 4096, E_ = 16384, G_ = 64;
constexpr int NODES_SZ = B_ * N_ * DD;   // 4,194,304
constexpr int EDGES_SZ = B_ * E_ * DD;   // 16,777,216
constexpr int BE_ = B_ * E_;             // 131,072
constexpr int BN_ = B_ * N_;             // 32,768
constexpr int BG_ = B_ * G_;             // 512
constexpr int GLOB_SZ = BG_ * DD;        // 65,536

constexpr int OFF_NODES = 0;
constexpr int OFF_EDGES = OFF_NODES + NODES_SZ;
constexpr int OFF_RECV  = OFF_EDGES + EDGES_SZ;
constexpr int OFF_SEND  = OFF_RECV + BE_;
constexpr int OFF_GLOB  = OFF_SEND + BE_;
constexpr int OFF_NGI   = OFF_GLOB + GLOB_SZ;
constexpr int OFF_EGI   = OFF_NGI + BN_;

// ws layout (float-element offsets)
constexpr int WS_EAGG  = 0;                       // [B,G,D] f32
constexpr int WS_NAGG  = WS_EAGG + GLOB_SZ;       // [B,G,D] f32
constexpr int WS_CNT   = WS_NAGG + GLOB_SZ;       // int [B*N]   (zeroed)
constexpr int WS_GCNTE = WS_CNT + BN_;            // int [512]   (zeroed)
constexpr int WS_GCNTN = WS_GCNTE + 512;          // int [512]   (zeroed)
constexpr int WS_RS    = WS_GCNTN + 512;          // int [B*N]
constexpr int WS_CUR   = WS_RS + BN_;             // int [B*N]
constexpr int WS_ELIST = WS_CUR + BN_;            // int [B*E]
constexpr int WS_GOFFE = WS_ELIST + BE_;          // int [512]
constexpr int WS_GCURE = WS_GOFFE + 512;          // int [512]
constexpr int WS_GOFFN = WS_GCURE + 512;          // int [512]
constexpr int WS_GCURN = WS_GOFFN + 512;          // int [512]
constexpr int WS_GELE  = WS_GCURN + 512;          // int [B*E]
constexpr int WS_GELN  = WS_GELE + BE_;           // int [B*N]
constexpr int WS_ADJB  = WS_GELN + BN_;           // u16 [B,N,D] -> BN*DD/2 f
constexpr int WS_NODB  = WS_ADJB + (BN_ * DD) / 2;
constexpr int WS_GLOBB = WS_NODB + (BN_ * DD) / 2;   // u16 [B,G,D]
constexpr int WS_WET   = WS_GLOBB + GLOB_SZ / 2;     // u16 [128*512]
constexpr int WS_WNT   = WS_WET + 32768;             // u16 [128*384]
// total ~4.82M floats = ~19.3 MB

__device__ inline u16 f2bf(float f) {
    union { float f; unsigned u; } v; v.f = f;
    return (u16)((v.u + 0x7fffu + ((v.u >> 16) & 1u)) >> 16);
}
__device__ inline short8 pack8(float4 a, float4 b) {
    short8 r;
    r[0] = (short)f2bf(a.x); r[1] = (short)f2bf(a.y);
    r[2] = (short)f2bf(a.z); r[3] = (short)f2bf(a.w);
    r[4] = (short)f2bf(b.x); r[5] = (short)f2bf(b.y);
    r[6] = (short)f2bf(b.z); r[7] = (short)f2bf(b.w);
    return r;
}

__global__ __launch_bounds__(256) void prep_w(
    const float* __restrict__ We, const float* __restrict__ Wn,
    u16* __restrict__ WeT, u16* __restrict__ WnT) {
    const int i = blockIdx.x * blockDim.x + threadIdx.x;
    if (i < DD * 512) {                       // WeT[n][k] = bf16(We[k][n])
        const int n = i >> 9, k = i & 511;
        WeT[i] = f2bf(We[k * DD + n]);
    } else {
        const int j = i - DD * 512;
        if (j < DD * 384) {                   // WnT[n][k] = bf16(Wn[k][n])
            const int n = j / 384, k = j - n * 384;
            WnT[j] = f2bf(Wn[k * DD + n]);
        }
    }
}

// nodes/glob -> bf16 copies (gather targets)
__global__ __launch_bounds__(256) void cast_bf16(
    const float* __restrict__ nodes, const float* __restrict__ glob,
    u16* __restrict__ nodesB, u16* __restrict__ globB) {
    const int i = blockIdx.x * 256 + threadIdx.x;    // one short8 each
    const int NT = NODES_SZ / 8;                     // 524288
    if (i < NT) {
        const float4 a = *(const float4*)(nodes + (long)i * 8);
        const float4 b = *(const float4*)(nodes + (long)i * 8 + 4);
        *(short8*)(nodesB + (long)i * 8) = pack8(a, b);
    } else {
        const int j = i - NT;                        // < GLOB_SZ/8 = 8192
        const float4 a = *(const float4*)(glob + (long)j * 8);
        const float4 b = *(const float4*)(glob + (long)j * 8 + 4);
        *(short8*)(globB + (long)j * 8) = pack8(a, b);
    }
}

// idx passthrough copies (as float) + zero cnt/gcnt region
__global__ __launch_bounds__(256) void init_misc(
    const int* __restrict__ recv, const int* __restrict__ send,
    const int* __restrict__ ngi, const int* __restrict__ egi,
    float* __restrict__ out, int* __restrict__ zbase) {
    const int i = blockIdx.x * 256 + threadIdx.x;
    const int total = 3 * BE_ + BN_;                 // 425984
    if (i < total) {
        if (i < BE_)                 out[OFF_RECV + i] = (float)recv[i];
        else if (i < 2 * BE_)        out[OFF_SEND + (i - BE_)] = (float)send[i - BE_];
        else if (i < 2 * BE_ + BN_)  out[OFF_NGI + (i - 2 * BE_)] = (float)ngi[i - 2 * BE_];
        else                         out[OFF_EGI + (i - 2 * BE_ - BN_)] = (float)egi[i - 2 * BE_ - BN_];
    } else {
        const int j = i - total;                     // < 33792
        if (j < BN_ + 1024) zbase[j] = 0;
    }
}

// histograms: receiver (per-node), egi (per b,g), ngi (per b,g)
__global__ __launch_bounds__(256) void k_hist_all(
    const int* __restrict__ recv, const int* __restrict__ egi,
    const int* __restrict__ ngi,
    int* __restrict__ cnt, int* __restrict__ gcnt_e, int* __restrict__ gcnt_n) {
    const int i = blockIdx.x * 256 + threadIdx.x;    // 0..BE-1
    const int b = i >> 14;
    atomicAdd(&cnt[b * N_ + recv[i]], 1);
    atomicAdd(&gcnt_e[b * G_ + egi[i]], 1);
    if (i < BN_) atomicAdd(&gcnt_n[(i >> 12) * G_ + ngi[i]], 1);
}

// per-batch scans: receiver CSR (4096 bins) + egi/ngi group CSR (64 bins)
__global__ __launch_bounds__(1024) void k_scan(
    const int* __restrict__ cnt, int* __restrict__ rs, int* __restrict__ cur,
    const int* __restrict__ gcnt_e, int* __restrict__ goff_e, int* __restrict__ gcur_e,
    const int* __restrict__ gcnt_n, int* __restrict__ goff_n, int* __restrict__ gcur_n) {
    __shared__ int s[1024];
    const int b = blockIdx.x;
    const int t = threadIdx.x;
    const int base = b * N_;
    int c[4];
    int sum = 0;
    #pragma unroll
    for (int i = 0; i < 4; ++i) { c[i] = cnt[base + 4 * t + i]; sum += c[i]; }
    s[t] = sum;
    __syncthreads();
    for (int off = 1; off < 1024; off <<= 1) {
        int v = s[t];
        if (t >= off) v += s[t - off];
        __syncthreads();
        s[t] = v;
        __syncthreads();
    }
    int eb = s[t] - sum;
    #pragma unroll
    for (int i = 0; i < 4; ++i) {
        rs[base + 4 * t + i] = eb;
        cur[base + 4 * t + i] = eb;
        eb += c[i];
    }
    // --- egi group scan (64 bins) ---
    __syncthreads();
    int gv = 0;
    if (t < G_) { gv = gcnt_e[b * G_ + t]; s[t] = gv; }
    __syncthreads();
    for (int off = 1; off < G_; off <<= 1) {
        int v = 0;
        if (t < G_) { v = s[t]; if (t >= off) v += s[t - off]; }
        __syncthreads();
        if (t < G_) s[t] = v;
        __syncthreads();
    }
    if (t < G_) {
        const int ex = s[t] - gv;
        goff_e[b * G_ + t] = ex;
        gcur_e[b * G_ + t] = ex;
    }
    // --- ngi group scan (64 bins) ---
    __syncthreads();
    if (t < G_) { gv = gcnt_n[b * G_ + t]; s[t] = gv; }
    __syncthreads();
    for (int off = 1; off < G_; off <<= 1) {
        int v = 0;
        if (t < G_) { v = s[t]; if (t >= off) v += s[t - off]; }
        __syncthreads();
        if (t < G_) s[t] = v;
        __syncthreads();
    }
    if (t < G_) {
        const int ex = s[t] - gv;
        goff_n[b * G_ + t] = ex;
        gcur_n[b * G_ + t] = ex;
    }
}

__global__ __launch_bounds__(256) void k_fill_all(
    const int* __restrict__ recv, const int* __restrict__ egi,
    const int* __restrict__ ngi,
    int* __restrict__ cur, int* __restrict__ elist,
    int* __restrict__ gcur_e, int* __restrict__ gelist_e,
    int* __restrict__ gcur_n, int* __restrict__ gelist_n) {
    const int i = blockIdx.x * 256 + threadIdx.x;    // 0..BE-1
    const int b = i >> 14;
    const int s1 = atomicAdd(&cur[b * N_ + recv[i]], 1);
    elist[b * E_ + s1] = i;
    const int s2 = atomicAdd(&gcur_e[b * G_ + egi[i]], 1);
    gelist_e[b * E_ + s2] = i;
    if (i < BN_) {
        const int b2 = i >> 12;
        const int s3 = atomicAdd(&gcur_n[b2 * G_ + ngi[i]], 1);
        gelist_n[b2 * N_ + s3] = i;
    }
}

// -------- edge GEMM: 16 rows x 64 cols per wave, reg-direct, no LDS --------
__global__ __launch_bounds__(256, 8) void edge_mfma(
    const float* __restrict__ edges, const u16* __restrict__ nodesB,
    const u16* __restrict__ globB,
    const int* __restrict__ receivers, const int* __restrict__ senders,
    const int* __restrict__ egi,
    const u16* __restrict__ WeT, const float* __restrict__ be,
    float* __restrict__ uE) {
    const int tid = threadIdx.x;
    const int wv = tid >> 6, l = tid & 63;
    const int wm = wv >> 1, wn = wv & 1;
    const int fr = l & 15, fg = l >> 4;
    const int row0 = blockIdx.x * 32 + wm * 16;
    const int bb = blockIdx.x >> 9;               // 512 blocks per batch
    const int R = row0 + fr;

    const float* pE = edges + (long)R * DD;
    const u16* pS = nodesB + ((long)bb * N_ + senders[R]) * DD;
    const u16* pR = nodesB + ((long)bb * N_ + receivers[R]) * DD;
    const u16* pG = globB + ((long)bb * G_ + egi[R]) * DD;

    f32x4 acc[4];
    const f32x4 fz = {0.f, 0.f, 0.f, 0.f};
    #pragma unroll
    for (int i = 0; i < 4; ++i) acc[i] = fz;

    const u16* bbp = WeT + (long)(wn * 64 + fr) * 512 + fg * 8;

    #pragma unroll
    for (int seg = 0; seg < 4; ++seg) {
        #pragma unroll
        for (int ss = 0; ss < 4; ++ss) {
            const int off = ss * 32 + fg * 8;
            short8 a;
            if (seg == 0) {
                const float4 x = *(const float4*)(pE + off);
                const float4 y = *(const float4*)(pE + off + 4);
                a = pack8(x, y);
            } else {
                const u16* p = (seg == 1) ? pS : (seg == 2) ? pR : pG;
                a = *(const short8*)(p + off);
            }
            const u16* bp = bbp + seg * 128 + ss * 32;
            #pragma unroll
            for (int nt = 0; nt < 4; ++nt) {
                const short8 b = *(const short8*)(bp + nt * 8192);
                acc[nt] = __builtin_amdgcn_mfma_f32_16x16x32_bf16(a, b, acc[nt], 0, 0, 0);
            }
        }
    }

    #pragma unroll
    for (int nt = 0; nt < 4; ++nt) {
        const int c = wn * 64 + nt * 16 + fr;
        const float bias = be[c];
        #pragma unroll
        for (int r = 0; r < 4; ++r) {
            const int rr = row0 + fg * 4 + r;
            uE[(long)rr * DD + c] = fmaxf(acc[nt][r] + bias, 0.f);
        }
    }
}

// -------- adj = CSR gather-sum of u_e rows, written as bf16 --------
__global__ __launch_bounds__(256) void adj_gather(
    const int* __restrict__ rs, const int* __restrict__ cnt,
    const int* __restrict__ elist, const float* __restrict__ uE,
    u16* __restrict__ adjB) {
    const int tid = threadIdx.x;
    const int row = blockIdx.x * 64 + (tid >> 2);
    const int q = tid & 3;
    const int bb = row >> 12;
    const int start = rs[row], deg = cnt[row];
    const int* lp = elist + (long)bb * E_ + start;
    float4 a[8];
    #pragma unroll
    for (int j = 0; j < 8; ++j) a[j] = {0.f, 0.f, 0.f, 0.f};
    for (int i = 0; i < deg; ++i) {
        const float* up = uE + (long)lp[i] * DD + q * 32;
        #pragma unroll
        for (int j = 0; j < 8; ++j) {
            const float4 v = *(const float4*)(up + j * 4);
            a[j].x += v.x; a[j].y += v.y; a[j].z += v.z; a[j].w += v.w;
        }
    }
    u16* dst = adjB + (long)row * DD + q * 32;
    #pragma unroll
    for (int j = 0; j < 4; ++j)
        *(short8*)(dst + j * 8) = pack8(a[2 * j], a[2 * j + 1]);
}

// -------- node GEMM: all-bf16 A, 16x64 per wave --------
__global__ __launch_bounds__(256, 8) void node_mfma(
    const u16* __restrict__ nodesB, const u16* __restrict__ adjB,
    const u16* __restrict__ globB, const int* __restrict__ ngi,
    const u16* __restrict__ WnT, const float* __restrict__ bn,
    float* __restrict__ uN) {
    const int tid = threadIdx.x;
    const int wv = tid >> 6, l = tid & 63;
    const int wm = wv >> 1, wn = wv & 1;
    const int fr = l & 15, fg = l >> 4;
    const int row0 = blockIdx.x * 32 + wm * 16;
    const int bb = blockIdx.x >> 7;               // 128 blocks per batch
    const int R = row0 + fr;

    const u16* pN = nodesB + (long)R * DD;
    const u16* pA = adjB + (long)R * DD;
    const u16* pG = globB + ((long)bb * G_ + ngi[R]) * DD;

    f32x4 acc[4];
    const f32x4 fz = {0.f, 0.f, 0.f, 0.f};
    #pragma unroll
    for (int i = 0; i < 4; ++i) acc[i] = fz;

    const u16* bbp = WnT + (long)(wn * 64 + fr) * 384 + fg * 8;

    #pragma unroll
    for (int seg = 0; seg < 3; ++seg) {
        const u16* p = (seg == 0) ? pN : (seg == 1) ? pA : pG;
        #pragma unroll
        for (int ss = 0; ss < 4; ++ss) {
            const short8 a = *(const short8*)(p + ss * 32 + fg * 8);
            const u16* bp = bbp + seg * 128 + ss * 32;
            #pragma unroll
            for (int nt = 0; nt < 4; ++nt) {
                const short8 b = *(const short8*)(bp + nt * 6144);
                acc[nt] = __builtin_amdgcn_mfma_f32_16x16x32_bf16(a, b, acc[nt], 0, 0, 0);
            }
        }
    }

    #pragma unroll
    for (int nt = 0; nt < 4; ++nt) {
        const int c = wn * 64 + nt * 16 + fr;
        const float bias = bn[c];
        #pragma unroll
        for (int r = 0; r < 4; ++r) {
            const int rr = row0 + fg * 4 + r;
            uN[(long)rr * DD + c] = fmaxf(acc[nt][r] + bias, 0.f);
        }
    }
}

// -------- aggregate + fused residual (in-place): one block per (b,g) -------
__global__ __launch_bounds__(256) void agg_resid(
    const int* __restrict__ gcnt, const int* __restrict__ goff,
    const int* __restrict__ gelist, int spb,
    const float* __restrict__ xin, const float* __restrict__ w_res,
    float* __restrict__ u /* in-place -> x_out */, float* __restrict__ agg) {
    __shared__ float accl[256];
    const int bg = blockIdx.x;                 // 0..511
    const int b = bg >> 6;
    const int tid = threadIdx.x, col = tid & 127, sub = tid >> 7;
    const int m = gcnt[bg];
    const int* lp = gelist + (long)b * spb + goff[bg];
    const float wr = w_res[0];
    float acc = 0.f;
    for (int j = sub; j < m; j += 2) {
        const long re = (long)lp[j] * DD + col;
        const float v = u[re];
        acc += v;
        u[re] = xin[re] + wr * v;
    }
    accl[tid] = acc;
    __syncthreads();
    if (tid < 128) agg[(long)bg * DD + tid] = accl[tid] + accl[tid + 128];
}

// ---------------- global block: 512 rows, K=384, fp32 VALU ----------------
__global__ __launch_bounds__(128) void global_block(
    const float* __restrict__ nagg, const float* __restrict__ eagg,
    const float* __restrict__ glob,
    const float* __restrict__ Wg, const float* __restrict__ bg,
    const float* __restrict__ w_res, float* __restrict__ out) {
    __shared__ float gin[384];
    const int row = blockIdx.x;
    const int tid = threadIdx.x;
    gin[tid]       = nagg[row * DD + tid];
    gin[128 + tid] = eagg[row * DD + tid];
    gin[256 + tid] = glob[row * DD + tid];
    __syncthreads();
    float acc = bg[tid];
    #pragma unroll 4
    for (int k = 0; k < 384; ++k) acc += gin[k] * Wg[k * DD + tid];
    const float upd = fmaxf(acc, 0.f);
    out[OFF_GLOB + row * DD + tid] = glob[row * DD + tid] + w_res[0] * upd;
}

extern "C" void kernel_launch(void* const* d_in, const int* in_sizes, int n_in,
                              void* d_out, int out_size, void* d_ws, size_t ws_size,
                              hipStream_t stream) {
    const float* nodes     = (const float*)d_in[0];
    const float* edges     = (const float*)d_in[1];
    const int*   receivers = (const int*)d_in[2];
    const int*   senders   = (const int*)d_in[3];
    const float* glob      = (const float*)d_in[4];
    const int*   ngi       = (const int*)d_in[5];
    const int*   egi       = (const int*)d_in[6];
    const float* We        = (const float*)d_in[7];
    const float* be        = (const float*)d_in[8];
    const float* Wn        = (const float*)d_in[9];
    const float* bn        = (const float*)d_in[10];
    const float* Wg        = (const float*)d_in[11];
    const float* bg        = (const float*)d_in[12];
    const float* w_res     = (const float*)d_in[13];
    float* out = (float*)d_out;
    float* ws  = (float*)d_ws;

    float* eagg = ws + WS_EAGG;
    float* nagg = ws + WS_NAGG;
    int* cnt     = (int*)(ws + WS_CNT);
    int* gcnt_e  = (int*)(ws + WS_GCNTE);
    int* gcnt_n  = (int*)(ws + WS_GCNTN);
    int* rs      = (int*)(ws + WS_RS);
    int* cur     = (int*)(ws + WS_CUR);
    int* elist   = (int*)(ws + WS_ELIST);
    int* goff_e  = (int*)(ws + WS_GOFFE);
    int* gcur_e  = (int*)(ws + WS_GCURE);
    int* goff_n  = (int*)(ws + WS_GOFFN);
    int* gcur_n  = (int*)(ws + WS_GCURN);
    int* gelist_e = (int*)(ws + WS_GELE);
    int* gelist_n = (int*)(ws + WS_GELN);
    u16* adjB   = (u16*)(ws + WS_ADJB);
    u16* nodesB = (u16*)(ws + WS_NODB);
    u16* globB  = (u16*)(ws + WS_GLOBB);
    u16* WeT    = (u16*)(ws + WS_WET);
    u16* WnT    = (u16*)(ws + WS_WNT);

    float* uE = out + OFF_EDGES;   // u_e lives here, then becomes edges_out
    float* uN = out + OFF_NODES;   // u_n lives here, then becomes nodes_out

    hipLaunchKernelGGL(prep_w, dim3(448), dim3(256), 0, stream, We, Wn, WeT, WnT);
    hipLaunchKernelGGL(cast_bf16, dim3(2080), dim3(256), 0, stream,
                       nodes, glob, nodesB, globB);
    hipLaunchKernelGGL(init_misc, dim3(1796), dim3(256), 0, stream,
                       receivers, senders, ngi, egi, out, cnt);
    hipLaunchKernelGGL(k_hist_all, dim3(512), dim3(256), 0, stream,
                       receivers, egi, ngi, cnt, gcnt_e, gcnt_n);
    hipLaunchKernelGGL(k_scan, dim3(8), dim3(1024), 0, stream,
                       cnt, rs, cur, gcnt_e, goff_e, gcur_e, gcnt_n, goff_n, gcur_n);
    hipLaunchKernelGGL(k_fill_all, dim3(512), dim3(256), 0, stream,
                       receivers, egi, ngi, cur, elist, gcur_e, gelist_e,
                       gcur_n, gelist_n);
    hipLaunchKernelGGL(edge_mfma, dim3(BE_ / 32), dim3(256), 0, stream,
                       edges, nodesB, globB, receivers, senders, egi, WeT, be, uE);
    hipLaunchKernelGGL(adj_gather, dim3(BN_ / 64), dim3(256), 0, stream,
                       rs, cnt, elist, uE, adjB);
    hipLaunchKernelGGL(agg_resid, dim3(BG_), dim3(256), 0, stream,
                       gcnt_e, goff_e, gelist_e, E_, edges, w_res, uE, eagg);
    hipLaunchKernelGGL(node_mfma, dim3(BN_ / 32), dim3(256), 0, stream,
                       nodesB, adjB, globB, ngi, WnT, bn, uN);
    hipLaunchKernelGGL(agg_resid, dim3(BG_), dim3(256), 0, stream,
                       gcnt_n, goff_n, gelist_n, N_, nodes, w_res, uN, nagg);
    hipLaunchKernelGGL(global_block, dim3(BG_), dim3(128), 0, stream,
                       nagg, eagg, glob, Wg, bg, w_res, out);
}

// Round 6
// 305.833 us; speedup vs baseline: 1.4420x; 1.4420x over previous
//
#include <hip/hip_runtime.h>

// GraphNetworkLayer: B=8, N=4096, E=16384, G=64, D=128, fp32 in/out.
// Round 6: ILP x TLP rebalance.
//  - edge/node MFMA: 32 rows x 64 cols per wave (acc=32 VGPR), explicit
//    register double-buffer of A segments (8 loads issued before prior
//    segment's MFMAs), NO launch-bounds VGPR cap. XCD swizzle maps each
//    XCD to one batch (nodesB slice L2-resident).
//  - agg_resid: float4 per lane, 8 rows in flight, PART=4 column-split
//    (2048 blocks), partial aggs [PART][BG][128] summed in global_block.
//  - CSR trimmed: start = cur - cnt (rs/goff dropped). ws ~20.7 MB.
//  - No float atomics anywhere.

#define DD 128
typedef unsigned short u16;
typedef __attribute__((ext_vector_type(8))) short short8;   // 8 bf16
typedef __attribute__((ext_vector_type(4))) float f32x4;

constexpr int B_ = 8, N_ = 4096, E_ = 16384, G_ = 64;
constexpr int NODES_SZ = B_ * N_ * DD;   // 4,194,304
constexpr int EDGES_SZ = B_ * E_ * DD;   // 16,777,216
constexpr int BE_ = B_ * E_;             // 131,072
constexpr int BN_ = B_ * N_;             // 32,768
constexpr int BG_ = B_ * G_;             // 512
constexpr int GLOB_SZ = BG_ * DD;        // 65,536
constexpr int PART = 4;

constexpr int OFF_NODES = 0;
constexpr int OFF_EDGES = OFF_NODES + NODES_SZ;
constexpr int OFF_RECV  = OFF_EDGES + EDGES_SZ;
constexpr int OFF_SEND  = OFF_RECV + BE_;
constexpr int OFF_GLOB  = OFF_SEND + BE_;
constexpr int OFF_NGI   = OFF_GLOB + GLOB_SZ;
constexpr int OFF_EGI   = OFF_NGI + BN_;

// ws layout (float-element offsets)
constexpr int WS_EAGGP = 0;                          // [PART][BG][DD] f32
constexpr int WS_NAGGP = WS_EAGGP + PART * GLOB_SZ;  // [PART][BG][DD] f32
constexpr int WS_CNT   = WS_NAGGP + PART * GLOB_SZ;  // int [B*N] (zeroed)
constexpr int WS_GCNTE = WS_CNT + BN_;               // int [512] (zeroed)
constexpr int WS_GCNTN = WS_GCNTE + 512;             // int [512] (zeroed)
constexpr int WS_CUR   = WS_GCNTN + 512;             // int [B*N]
constexpr int WS_GCURE = WS_CUR + BN_;               // int [512]
constexpr int WS_GCURN = WS_GCURE + 512;             // int [512]
constexpr int WS_ELIST = WS_GCURN + 512;             // int [B*E]
constexpr int WS_GELE  = WS_ELIST + BE_;             // int [B*E]
constexpr int WS_GELN  = WS_GELE + BE_;              // int [B*N]
constexpr int WS_ADJB  = WS_GELN + BN_;              // u16 [B,N,D]
constexpr int WS_NODB  = WS_ADJB + (BN_ * DD) / 2;   // u16 [B,N,D]
constexpr int WS_GLOBB = WS_NODB + (BN_ * DD) / 2;   // u16 [B,G,D]
constexpr int WS_WET   = WS_GLOBB + GLOB_SZ / 2;     // u16 [128*512]
constexpr int WS_WNT   = WS_WET + 32768;             // u16 [128*384]
// total ~5.17M floats = ~20.7 MB

__device__ inline u16 f2bf(float f) {
    union { float f; unsigned u; } v; v.f = f;
    return (u16)((v.u + 0x7fffu + ((v.u >> 16) & 1u)) >> 16);
}
__device__ inline short8 pack8(float4 a, float4 b) {
    short8 r;
    r[0] = (short)f2bf(a.x); r[1] = (short)f2bf(a.y);
    r[2] = (short)f2bf(a.z); r[3] = (short)f2bf(a.w);
    r[4] = (short)f2bf(b.x); r[5] = (short)f2bf(b.y);
    r[6] = (short)f2bf(b.z); r[7] = (short)f2bf(b.w);
    return r;
}

__global__ __launch_bounds__(256) void prep_w(
    const float* __restrict__ We, const float* __restrict__ Wn,
    u16* __restrict__ WeT, u16* __restrict__ WnT) {
    const int i = blockIdx.x * blockDim.x + threadIdx.x;
    if (i < DD * 512) {                       // WeT[n][k] = bf16(We[k][n])
        const int n = i >> 9, k = i & 511;
        WeT[i] = f2bf(We[k * DD + n]);
    } else {
        const int j = i - DD * 512;
        if (j < DD * 384) {                   // WnT[n][k] = bf16(Wn[k][n])
            const int n = j / 384, k = j - n * 384;
            WnT[j] = f2bf(Wn[k * DD + n]);
        }
    }
}

// nodes/glob -> bf16 copies (gather targets)
__global__ __launch_bounds__(256) void cast_bf16(
    const float* __restrict__ nodes, const float* __restrict__ glob,
    u16* __restrict__ nodesB, u16* __restrict__ globB) {
    const int i = blockIdx.x * 256 + threadIdx.x;
    const int NT = NODES_SZ / 8;
    if (i < NT) {
        const float4 a = *(const float4*)(nodes + (long)i * 8);
        const float4 b = *(const float4*)(nodes + (long)i * 8 + 4);
        *(short8*)(nodesB + (long)i * 8) = pack8(a, b);
    } else {
        const int j = i - NT;
        const float4 a = *(const float4*)(glob + (long)j * 8);
        const float4 b = *(const float4*)(glob + (long)j * 8 + 4);
        *(short8*)(globB + (long)j * 8) = pack8(a, b);
    }
}

// idx passthrough copies (as float) + zero cnt/gcnt region
__global__ __launch_bounds__(256) void init_misc(
    const int* __restrict__ recv, const int* __restrict__ send,
    const int* __restrict__ ngi, const int* __restrict__ egi,
    float* __restrict__ out, int* __restrict__ zbase) {
    const int i = blockIdx.x * 256 + threadIdx.x;
    const int total = 3 * BE_ + BN_;
    if (i < total) {
        if (i < BE_)                 out[OFF_RECV + i] = (float)recv[i];
        else if (i < 2 * BE_)        out[OFF_SEND + (i - BE_)] = (float)send[i - BE_];
        else if (i < 2 * BE_ + BN_)  out[OFF_NGI + (i - 2 * BE_)] = (float)ngi[i - 2 * BE_];
        else                         out[OFF_EGI + (i - 2 * BE_ - BN_)] = (float)egi[i - 2 * BE_ - BN_];
    } else {
        const int j = i - total;
        if (j < BN_ + 1024) zbase[j] = 0;
    }
}

__global__ __launch_bounds__(256) void k_hist_all(
    const int* __restrict__ recv, const int* __restrict__ egi,
    const int* __restrict__ ngi,
    int* __restrict__ cnt, int* __restrict__ gcnt_e, int* __restrict__ gcnt_n) {
    const int i = blockIdx.x * 256 + threadIdx.x;
    const int b = i >> 14;
    atomicAdd(&cnt[b * N_ + recv[i]], 1);
    atomicAdd(&gcnt_e[b * G_ + egi[i]], 1);
    if (i < BN_) atomicAdd(&gcnt_n[(i >> 12) * G_ + ngi[i]], 1);
}

// per-batch exclusive scans -> cursors only (start recovered as cur - cnt)
__global__ __launch_bounds__(1024) void k_scan(
    const int* __restrict__ cnt, int* __restrict__ cur,
    const int* __restrict__ gcnt_e, int* __restrict__ gcur_e,
    const int* __restrict__ gcnt_n, int* __restrict__ gcur_n) {
    __shared__ int s[1024];
    const int b = blockIdx.x;
    const int t = threadIdx.x;
    const int base = b * N_;
    int c[4];
    int sum = 0;
    #pragma unroll
    for (int i = 0; i < 4; ++i) { c[i] = cnt[base + 4 * t + i]; sum += c[i]; }
    s[t] = sum;
    __syncthreads();
    for (int off = 1; off < 1024; off <<= 1) {
        int v = s[t];
        if (t >= off) v += s[t - off];
        __syncthreads();
        s[t] = v;
        __syncthreads();
    }
    int eb = s[t] - sum;
    #pragma unroll
    for (int i = 0; i < 4; ++i) { cur[base + 4 * t + i] = eb; eb += c[i]; }
    // egi group scan
    __syncthreads();
    int gv = 0;
    if (t < G_) { gv = gcnt_e[b * G_ + t]; s[t] = gv; }
    __syncthreads();
    for (int off = 1; off < G_; off <<= 1) {
        int v = 0;
        if (t < G_) { v = s[t]; if (t >= off) v += s[t - off]; }
        __syncthreads();
        if (t < G_) s[t] = v;
        __syncthreads();
    }
    if (t < G_) gcur_e[b * G_ + t] = s[t] - gv;
    // ngi group scan
    __syncthreads();
    if (t < G_) { gv = gcnt_n[b * G_ + t]; s[t] = gv; }
    __syncthreads();
    for (int off = 1; off < G_; off <<= 1) {
        int v = 0;
        if (t < G_) { v = s[t]; if (t >= off) v += s[t - off]; }
        __syncthreads();
        if (t < G_) s[t] = v;
        __syncthreads();
    }
    if (t < G_) gcur_n[b * G_ + t] = s[t] - gv;
}

__global__ __launch_bounds__(256) void k_fill_all(
    const int* __restrict__ recv, const int* __restrict__ egi,
    const int* __restrict__ ngi,
    int* __restrict__ cur, int* __restrict__ elist,
    int* __restrict__ gcur_e, int* __restrict__ gelist_e,
    int* __restrict__ gcur_n, int* __restrict__ gelist_n) {
    const int i = blockIdx.x * 256 + threadIdx.x;
    const int b = i >> 14;
    const int s1 = atomicAdd(&cur[b * N_ + recv[i]], 1);
    elist[b * E_ + s1] = i;
    const int s2 = atomicAdd(&gcur_e[b * G_ + egi[i]], 1);
    gelist_e[b * E_ + s2] = i;
    if (i < BN_) {
        const int b2 = i >> 12;
        const int s3 = atomicAdd(&gcur_n[b2 * G_ + ngi[i]], 1);
        gelist_n[b2 * N_ + s3] = i;
    }
}

// -------- edge GEMM: 32 rows x 64 cols per wave, reg double-buffered A ----
__global__ __launch_bounds__(256) void edge_mfma(
    const float* __restrict__ edges, const u16* __restrict__ nodesB,
    const u16* __restrict__ globB,
    const int* __restrict__ receivers, const int* __restrict__ senders,
    const int* __restrict__ egi,
    const u16* __restrict__ WeT, const float* __restrict__ be,
    float* __restrict__ uE) {
    const int tid = threadIdx.x;
    const int wv = tid >> 6, l = tid & 63;
    const int wm = wv >> 1, wn = wv & 1;
    const int fr = l & 15, fg = l >> 4;
    const int bid = blockIdx.x;                    // 2048 blocks
    const int swz = (bid & 7) * 256 + (bid >> 3);  // XCD x -> batch x
    const int row0 = swz * 64 + wm * 32;
    const int bb = swz >> 8;                       // 256 blocks/batch
    const int R0 = row0 + fr, R1 = R0 + 16;

    const float* pE0 = edges + (long)R0 * DD;
    const float* pE1 = edges + (long)R1 * DD;
    const u16* nb = nodesB + (long)bb * N_ * DD;
    const u16* pS0 = nb + (long)senders[R0] * DD;
    const u16* pS1 = nb + (long)senders[R1] * DD;
    const u16* pR0 = nb + (long)receivers[R0] * DD;
    const u16* pR1 = nb + (long)receivers[R1] * DD;
    const u16* pG0 = globB + ((long)bb * G_ + egi[R0]) * DD;
    const u16* pG1 = globB + ((long)bb * G_ + egi[R1]) * DD;

    f32x4 acc0[4], acc1[4];
    const f32x4 fz = {0.f, 0.f, 0.f, 0.f};
    #pragma unroll
    for (int i = 0; i < 4; ++i) { acc0[i] = fz; acc1[i] = fz; }

    const u16* bbp = WeT + (long)(wn * 64 + fr) * 512 + fg * 8;

    // seg0 (edges, fp32): load + pack
    short8 A0[4], A1[4];
    #pragma unroll
    for (int ss = 0; ss < 4; ++ss) {
        const int off = ss * 32 + fg * 8;
        A0[ss] = pack8(*(const float4*)(pE0 + off), *(const float4*)(pE0 + off + 4));
        A1[ss] = pack8(*(const float4*)(pE1 + off), *(const float4*)(pE1 + off + 4));
    }

    #pragma unroll
    for (int seg = 0; seg < 4; ++seg) {
        short8 nA0[4], nA1[4];
        if (seg < 3) {   // prefetch next segment into the other buffer
            const u16* q0 = (seg == 0) ? pS0 : (seg == 1) ? pR0 : pG0;
            const u16* q1 = (seg == 0) ? pS1 : (seg == 1) ? pR1 : pG1;
            #pragma unroll
            for (int ss = 0; ss < 4; ++ss) {
                nA0[ss] = *(const short8*)(q0 + ss * 32 + fg * 8);
                nA1[ss] = *(const short8*)(q1 + ss * 32 + fg * 8);
            }
        }
        const u16* bsp = bbp + seg * 128;
        #pragma unroll
        for (int ss = 0; ss < 4; ++ss) {
            const u16* bp = bsp + ss * 32;
            #pragma unroll
            for (int nt = 0; nt < 4; ++nt) {
                const short8 b = *(const short8*)(bp + nt * 8192);
                acc0[nt] = __builtin_amdgcn_mfma_f32_16x16x32_bf16(A0[ss], b, acc0[nt], 0, 0, 0);
                acc1[nt] = __builtin_amdgcn_mfma_f32_16x16x32_bf16(A1[ss], b, acc1[nt], 0, 0, 0);
            }
        }
        if (seg < 3) {
            #pragma unroll
            for (int ss = 0; ss < 4; ++ss) { A0[ss] = nA0[ss]; A1[ss] = nA1[ss]; }
        }
    }

    #pragma unroll
    for (int nt = 0; nt < 4; ++nt) {
        const int c = wn * 64 + nt * 16 + fr;
        const float bias = be[c];
        #pragma unroll
        for (int r = 0; r < 4; ++r) {
            const int rr = row0 + fg * 4 + r;
            uE[(long)rr * DD + c] = fmaxf(acc0[nt][r] + bias, 0.f);
            uE[(long)(rr + 16) * DD + c] = fmaxf(acc1[nt][r] + bias, 0.f);
        }
    }
}

// -------- adj = CSR gather-sum of u_e rows, written as bf16 --------
__global__ __launch_bounds__(256) void adj_gather(
    const int* __restrict__ cur, const int* __restrict__ cnt,
    const int* __restrict__ elist, const float* __restrict__ uE,
    u16* __restrict__ adjB) {
    const int tid = threadIdx.x;
    const int row = blockIdx.x * 64 + (tid >> 2);
    const int q = tid & 3;
    const int bb = row >> 12;
    const int deg = cnt[row];
    const int start = cur[row] - deg;
    const int* lp = elist + (long)bb * E_ + start;
    float4 a[8];
    #pragma unroll
    for (int j = 0; j < 8; ++j) a[j] = {0.f, 0.f, 0.f, 0.f};
    for (int i = 0; i < deg; ++i) {
        const float* up = uE + (long)lp[i] * DD + q * 32;
        #pragma unroll
        for (int j = 0; j < 8; ++j) {
            const float4 v = *(const float4*)(up + j * 4);
            a[j].x += v.x; a[j].y += v.y; a[j].z += v.z; a[j].w += v.w;
        }
    }
    u16* dst = adjB + (long)row * DD + q * 32;
    #pragma unroll
    for (int j = 0; j < 4; ++j)
        *(short8*)(dst + j * 8) = pack8(a[2 * j], a[2 * j + 1]);
}

// -------- node GEMM: 32 rows x 64 cols per wave, all-bf16 A --------
__global__ __launch_bounds__(256) void node_mfma(
    const u16* __restrict__ nodesB, const u16* __restrict__ adjB,
    const u16* __restrict__ globB, const int* __restrict__ ngi,
    const u16* __restrict__ WnT, const float* __restrict__ bn,
    float* __restrict__ uN) {
    const int tid = threadIdx.x;
    const int wv = tid >> 6, l = tid & 63;
    const int wm = wv >> 1, wn = wv & 1;
    const int fr = l & 15, fg = l >> 4;
    const int bid = blockIdx.x;                   // 512 blocks
    const int swz = (bid & 7) * 64 + (bid >> 3);  // XCD x -> batch x
    const int row0 = swz * 64 + wm * 32;
    const int bb = swz >> 6;                      // 64 blocks/batch
    const int R0 = row0 + fr, R1 = R0 + 16;

    const u16* pN0 = nodesB + (long)R0 * DD;
    const u16* pN1 = nodesB + (long)R1 * DD;
    const u16* pA0 = adjB + (long)R0 * DD;
    const u16* pA1 = adjB + (long)R1 * DD;
    const u16* pG0 = globB + ((long)bb * G_ + ngi[R0]) * DD;
    const u16* pG1 = globB + ((long)bb * G_ + ngi[R1]) * DD;

    f32x4 acc0[4], acc1[4];
    const f32x4 fz = {0.f, 0.f, 0.f, 0.f};
    #pragma unroll
    for (int i = 0; i < 4; ++i) { acc0[i] = fz; acc1[i] = fz; }

    const u16* bbp = WnT + (long)(wn * 64 + fr) * 384 + fg * 8;

    short8 A0[4], A1[4];
    #pragma unroll
    for (int ss = 0; ss < 4; ++ss) {
        A0[ss] = *(const short8*)(pN0 + ss * 32 + fg * 8);
        A1[ss] = *(const short8*)(pN1 + ss * 32 + fg * 8);
    }

    #pragma unroll
    for (int seg = 0; seg < 3; ++seg) {
        short8 nA0[4], nA1[4];
        if (seg < 2) {
            const u16* q0 = (seg == 0) ? pA0 : pG0;
            const u16* q1 = (seg == 0) ? pA1 : pG1;
            #pragma unroll
            for (int ss = 0; ss < 4; ++ss) {
                nA0[ss] = *(const short8*)(q0 + ss * 32 + fg * 8);
                nA1[ss] = *(const short8*)(q1 + ss * 32 + fg * 8);
            }
        }
        const u16* bsp = bbp + seg * 128;
        #pragma unroll
        for (int ss = 0; ss < 4; ++ss) {
            const u16* bp = bsp + ss * 32;
            #pragma unroll
            for (int nt = 0; nt < 4; ++nt) {
                const short8 b = *(const short8*)(bp + nt * 6144);
                acc0[nt] = __builtin_amdgcn_mfma_f32_16x16x32_bf16(A0[ss], b, acc0[nt], 0, 0, 0);
                acc1[nt] = __builtin_amdgcn_mfma_f32_16x16x32_bf16(A1[ss], b, acc1[nt], 0, 0, 0);
            }
        }
        if (seg < 2) {
            #pragma unroll
            for (int ss = 0; ss < 4; ++ss) { A0[ss] = nA0[ss]; A1[ss] = nA1[ss]; }
        }
    }

    #pragma unroll
    for (int nt = 0; nt < 4; ++nt) {
        const int c = wn * 64 + nt * 16 + fr;
        const float bias = bn[c];
        #pragma unroll
        for (int r = 0; r < 4; ++r) {
            const int rr = row0 + fg * 4 + r;
            uN[(long)rr * DD + c] = fmaxf(acc0[nt][r] + bias, 0.f);
            uN[(long)(rr + 16) * DD + c] = fmaxf(acc1[nt][r] + bias, 0.f);
        }
    }
}

// -------- aggregate + fused residual, PART-way column split --------
__global__ __launch_bounds__(256) void agg_resid(
    const int* __restrict__ gcnt, const int* __restrict__ gcur,
    const int* __restrict__ gelist, int spb,
    const float* __restrict__ xin, const float* __restrict__ w_res,
    float* __restrict__ u /* in-place -> x_out */,
    float* __restrict__ aggp /* [PART][BG][DD] */) {
    __shared__ float accl[1024];
    const int bg = blockIdx.x >> 2;            // grid = BG*PART
    const int p  = blockIdx.x & 3;
    const int b = bg >> 6;
    const int tid = threadIdx.x;
    const int c4 = (tid & 31) << 2;
    const int sub = tid >> 5;                  // 0..7
    const int m = gcnt[bg];
    const int* lp = gelist + (long)b * spb + (gcur[bg] - m);
    const float wr = w_res[0];
    f32x4 acc = {0.f, 0.f, 0.f, 0.f};
    for (int j = p * 8 + sub; j < m; j += 32) {
        const long re = (long)lp[j] * DD + c4;
        const float4 v = *(const float4*)(u + re);
        const float4 x = *(const float4*)(xin + re);
        acc[0] += v.x; acc[1] += v.y; acc[2] += v.z; acc[3] += v.w;
        float4 o;
        o.x = x.x + wr * v.x; o.y = x.y + wr * v.y;
        o.z = x.z + wr * v.z; o.w = x.w + wr * v.w;
        *(float4*)(u + re) = o;
    }
    *(f32x4*)&accl[sub * 128 + c4] = acc;
    __syncthreads();
    if (tid < 128) {
        float s = 0.f;
        #pragma unroll
        for (int q = 0; q < 8; ++q) s += accl[q * 128 + tid];
        aggp[((long)p * BG_ + bg) * DD + tid] = s;
    }
}

// ---------------- global block: 512 rows, K=384, fp32 VALU ----------------
__global__ __launch_bounds__(128) void global_block(
    const float* __restrict__ naggp, const float* __restrict__ eaggp,
    const float* __restrict__ glob,
    const float* __restrict__ Wg, const float* __restrict__ bgb,
    const float* __restrict__ w_res, float* __restrict__ out) {
    __shared__ float gin[384];
    const int row = blockIdx.x;
    const int tid = threadIdx.x;
    float sn = 0.f, se = 0.f;
    #pragma unroll
    for (int p = 0; p < PART; ++p) {
        sn += naggp[((long)p * BG_ + row) * DD + tid];
        se += eaggp[((long)p * BG_ + row) * DD + tid];
    }
    gin[tid]       = sn;
    gin[128 + tid] = se;
    gin[256 + tid] = glob[row * DD + tid];
    __syncthreads();
    float acc = bgb[tid];
    #pragma unroll 4
    for (int k = 0; k < 384; ++k) acc += gin[k] * Wg[k * DD + tid];
    const float upd = fmaxf(acc, 0.f);
    out[OFF_GLOB + row * DD + tid] = glob[row * DD + tid] + w_res[0] * upd;
}

extern "C" void kernel_launch(void* const* d_in, const int* in_sizes, int n_in,
                              void* d_out, int out_size, void* d_ws, size_t ws_size,
                              hipStream_t stream) {
    const float* nodes     = (const float*)d_in[0];
    const float* edges     = (const float*)d_in[1];
    const int*   receivers = (const int*)d_in[2];
    const int*   senders   = (const int*)d_in[3];
    const float* glob      = (const float*)d_in[4];
    const int*   ngi       = (const int*)d_in[5];
    const int*   egi       = (const int*)d_in[6];
    const float* We        = (const float*)d_in[7];
    const float* be        = (const float*)d_in[8];
    const float* Wn        = (const float*)d_in[9];
    const float* bn        = (const float*)d_in[10];
    const float* Wg        = (const float*)d_in[11];
    const float* bg        = (const float*)d_in[12];
    const float* w_res     = (const float*)d_in[13];
    float* out = (float*)d_out;
    float* ws  = (float*)d_ws;

    float* eaggp = ws + WS_EAGGP;
    float* naggp = ws + WS_NAGGP;
    int* cnt      = (int*)(ws + WS_CNT);
    int* gcnt_e   = (int*)(ws + WS_GCNTE);
    int* gcnt_n   = (int*)(ws + WS_GCNTN);
    int* cur      = (int*)(ws + WS_CUR);
    int* gcur_e   = (int*)(ws + WS_GCURE);
    int* gcur_n   = (int*)(ws + WS_GCURN);
    int* elist    = (int*)(ws + WS_ELIST);
    int* gelist_e = (int*)(ws + WS_GELE);
    int* gelist_n = (int*)(ws + WS_GELN);
    u16* adjB   = (u16*)(ws + WS_ADJB);
    u16* nodesB = (u16*)(ws + WS_NODB);
    u16* globB  = (u16*)(ws + WS_GLOBB);
    u16* WeT    = (u16*)(ws + WS_WET);
    u16* WnT    = (u16*)(ws + WS_WNT);

    float* uE = out + OFF_EDGES;   // u_e, becomes edges_out after agg_resid
    float* uN = out + OFF_NODES;   // u_n, becomes nodes_out after agg_resid

    hipLaunchKernelGGL(prep_w, dim3(448), dim3(256), 0, stream, We, Wn, WeT, WnT);
    hipLaunchKernelGGL(cast_bf16, dim3(2080), dim3(256), 0, stream,
                       nodes, glob, nodesB, globB);
    hipLaunchKernelGGL(init_misc, dim3(1796), dim3(256), 0, stream,
                       receivers, senders, ngi, egi, out, cnt);
    hipLaunchKernelGGL(k_hist_all, dim3(512), dim3(256), 0, stream,
                       receivers, egi, ngi, cnt, gcnt_e, gcnt_n);
    hipLaunchKernelGGL(k_scan, dim3(8), dim3(1024), 0, stream,
                       cnt, cur, gcnt_e, gcur_e, gcnt_n, gcur_n);
    hipLaunchKernelGGL(k_fill_all, dim3(512), dim3(256), 0, stream,
                       receivers, egi, ngi, cur, elist, gcur_e, gelist_e,
                       gcur_n, gelist_n);
    hipLaunchKernelGGL(edge_mfma, dim3(BE_ / 64), dim3(256), 0, stream,
                       edges, nodesB, globB, receivers, senders, egi, WeT, be, uE);
    hipLaunchKernelGGL(adj_gather, dim3(BN_ / 64), dim3(256), 0, stream,
                       cur, cnt, elist, uE, adjB);
    hipLaunchKernelGGL(agg_resid, dim3(BG_ * PART), dim3(256), 0, stream,
                       gcnt_e, gcur_e, gelist_e, E_, edges, w_res, uE, eaggp);
    hipLaunchKernelGGL(node_mfma, dim3(BN_ / 64), dim3(256), 0, stream,
                       nodesB, adjB, globB, ngi, WnT, bn, uN);
    hipLaunchKernelGGL(agg_resid, dim3(BG_ * PART), dim3(256), 0, stream,
                       gcnt_n, gcur_n, gelist_n, N_, nodes, w_res, uN, naggp);
    hipLaunchKernelGGL(global_block, dim3(BG_), dim3(128), 0, stream,
                       naggp, eaggp, glob, Wg, bg, w_res, out);
}

// Round 7
// 246.254 us; speedup vs baseline: 1.7909x; 1.2419x over previous
//
#include <hip/hip_runtime.h>

// GraphNetworkLayer: B=8, N=4096, E=16384, G=64, D=128, fp32 in/out.
// Round 7: LDS-staged B (2-phase double-buffered pipeline) for both MFMA
// kernels; A stays reg-gathered (8 loads/lane/segment). B rows XOR-swizzled
// (ir ^ (n&7)<<4) against the 256B-stride bank conflict. Block = 128 rows x
// 64 cols (4 waves x 32 rows, M-rep 2), K in 128-wide segments.
// Dataflow identical to Round 6 otherwise. No float atomics anywhere.

#define DD 128
typedef unsigned short u16;
typedef __attribute__((ext_vector_type(8))) short short8;   // 8 bf16
typedef __attribute__((ext_vector_type(4))) float f32x4;

constexpr int B_ = 8, N_ = 4096, E_ = 16384, G_ = 64;
constexpr int NODES_SZ = B_ * N_ * DD;   // 4,194,304
constexpr int EDGES_SZ = B_ * E_ * DD;   // 16,777,216
constexpr int BE_ = B_ * E_;             // 131,072
constexpr int BN_ = B_ * N_;             // 32,768
constexpr int BG_ = B_ * G_;             // 512
constexpr int GLOB_SZ = BG_ * DD;        // 65,536
constexpr int PART = 4;

constexpr int OFF_NODES = 0;
constexpr int OFF_EDGES = OFF_NODES + NODES_SZ;
constexpr int OFF_RECV  = OFF_EDGES + EDGES_SZ;
constexpr int OFF_SEND  = OFF_RECV + BE_;
constexpr int OFF_GLOB  = OFF_SEND + BE_;
constexpr int OFF_NGI   = OFF_GLOB + GLOB_SZ;
constexpr int OFF_EGI   = OFF_NGI + BN_;

// ws layout (float-element offsets)
constexpr int WS_EAGGP = 0;                          // [PART][BG][DD] f32
constexpr int WS_NAGGP = WS_EAGGP + PART * GLOB_SZ;  // [PART][BG][DD] f32
constexpr int WS_CNT   = WS_NAGGP + PART * GLOB_SZ;  // int [B*N] (zeroed)
constexpr int WS_GCNTE = WS_CNT + BN_;               // int [512] (zeroed)
constexpr int WS_GCNTN = WS_GCNTE + 512;             // int [512] (zeroed)
constexpr int WS_CUR   = WS_GCNTN + 512;             // int [B*N]
constexpr int WS_GCURE = WS_CUR + BN_;               // int [512]
constexpr int WS_GCURN = WS_GCURE + 512;             // int [512]
constexpr int WS_ELIST = WS_GCURN + 512;             // int [B*E]
constexpr int WS_GELE  = WS_ELIST + BE_;             // int [B*E]
constexpr int WS_GELN  = WS_GELE + BE_;              // int [B*N]
constexpr int WS_ADJB  = WS_GELN + BN_;              // u16 [B,N,D]
constexpr int WS_NODB  = WS_ADJB + (BN_ * DD) / 2;   // u16 [B,N,D]
constexpr int WS_GLOBB = WS_NODB + (BN_ * DD) / 2;   // u16 [B,G,D]
constexpr int WS_WET   = WS_GLOBB + GLOB_SZ / 2;     // u16 [128*512]
constexpr int WS_WNT   = WS_WET + 32768;             // u16 [128*384]
// total ~5.17M floats = ~20.7 MB

__device__ inline u16 f2bf(float f) {
    union { float f; unsigned u; } v; v.f = f;
    return (u16)((v.u + 0x7fffu + ((v.u >> 16) & 1u)) >> 16);
}
__device__ inline short8 pack8(float4 a, float4 b) {
    short8 r;
    r[0] = (short)f2bf(a.x); r[1] = (short)f2bf(a.y);
    r[2] = (short)f2bf(a.z); r[3] = (short)f2bf(a.w);
    r[4] = (short)f2bf(b.x); r[5] = (short)f2bf(b.y);
    r[6] = (short)f2bf(b.z); r[7] = (short)f2bf(b.w);
    return r;
}

__global__ __launch_bounds__(256) void prep_w(
    const float* __restrict__ We, const float* __restrict__ Wn,
    u16* __restrict__ WeT, u16* __restrict__ WnT) {
    const int i = blockIdx.x * blockDim.x + threadIdx.x;
    if (i < DD * 512) {                       // WeT[n][k] = bf16(We[k][n])
        const int n = i >> 9, k = i & 511;
        WeT[i] = f2bf(We[k * DD + n]);
    } else {
        const int j = i - DD * 512;
        if (j < DD * 384) {                   // WnT[n][k] = bf16(Wn[k][n])
            const int n = j / 384, k = j - n * 384;
            WnT[j] = f2bf(Wn[k * DD + n]);
        }
    }
}

__global__ __launch_bounds__(256) void cast_bf16(
    const float* __restrict__ nodes, const float* __restrict__ glob,
    u16* __restrict__ nodesB, u16* __restrict__ globB) {
    const int i = blockIdx.x * 256 + threadIdx.x;
    const int NT = NODES_SZ / 8;
    if (i < NT) {
        const float4 a = *(const float4*)(nodes + (long)i * 8);
        const float4 b = *(const float4*)(nodes + (long)i * 8 + 4);
        *(short8*)(nodesB + (long)i * 8) = pack8(a, b);
    } else {
        const int j = i - NT;
        const float4 a = *(const float4*)(glob + (long)j * 8);
        const float4 b = *(const float4*)(glob + (long)j * 8 + 4);
        *(short8*)(globB + (long)j * 8) = pack8(a, b);
    }
}

__global__ __launch_bounds__(256) void init_misc(
    const int* __restrict__ recv, const int* __restrict__ send,
    const int* __restrict__ ngi, const int* __restrict__ egi,
    float* __restrict__ out, int* __restrict__ zbase) {
    const int i = blockIdx.x * 256 + threadIdx.x;
    const int total = 3 * BE_ + BN_;
    if (i < total) {
        if (i < BE_)                 out[OFF_RECV + i] = (float)recv[i];
        else if (i < 2 * BE_)        out[OFF_SEND + (i - BE_)] = (float)send[i - BE_];
        else if (i < 2 * BE_ + BN_)  out[OFF_NGI + (i - 2 * BE_)] = (float)ngi[i - 2 * BE_];
        else                         out[OFF_EGI + (i - 2 * BE_ - BN_)] = (float)egi[i - 2 * BE_ - BN_];
    } else {
        const int j = i - total;
        if (j < BN_ + 1024) zbase[j] = 0;
    }
}

__global__ __launch_bounds__(256) void k_hist_all(
    const int* __restrict__ recv, const int* __restrict__ egi,
    const int* __restrict__ ngi,
    int* __restrict__ cnt, int* __restrict__ gcnt_e, int* __restrict__ gcnt_n) {
    const int i = blockIdx.x * 256 + threadIdx.x;
    const int b = i >> 14;
    atomicAdd(&cnt[b * N_ + recv[i]], 1);
    atomicAdd(&gcnt_e[b * G_ + egi[i]], 1);
    if (i < BN_) atomicAdd(&gcnt_n[(i >> 12) * G_ + ngi[i]], 1);
}

__global__ __launch_bounds__(1024) void k_scan(
    const int* __restrict__ cnt, int* __restrict__ cur,
    const int* __restrict__ gcnt_e, int* __restrict__ gcur_e,
    const int* __restrict__ gcnt_n, int* __restrict__ gcur_n) {
    __shared__ int s[1024];
    const int b = blockIdx.x;
    const int t = threadIdx.x;
    const int base = b * N_;
    int c[4];
    int sum = 0;
    #pragma unroll
    for (int i = 0; i < 4; ++i) { c[i] = cnt[base + 4 * t + i]; sum += c[i]; }
    s[t] = sum;
    __syncthreads();
    for (int off = 1; off < 1024; off <<= 1) {
        int v = s[t];
        if (t >= off) v += s[t - off];
        __syncthreads();
        s[t] = v;
        __syncthreads();
    }
    int eb = s[t] - sum;
    #pragma unroll
    for (int i = 0; i < 4; ++i) { cur[base + 4 * t + i] = eb; eb += c[i]; }
    __syncthreads();
    int gv = 0;
    if (t < G_) { gv = gcnt_e[b * G_ + t]; s[t] = gv; }
    __syncthreads();
    for (int off = 1; off < G_; off <<= 1) {
        int v = 0;
        if (t < G_) { v = s[t]; if (t >= off) v += s[t - off]; }
        __syncthreads();
        if (t < G_) s[t] = v;
        __syncthreads();
    }
    if (t < G_) gcur_e[b * G_ + t] = s[t] - gv;
    __syncthreads();
    if (t < G_) { gv = gcnt_n[b * G_ + t]; s[t] = gv; }
    __syncthreads();
    for (int off = 1; off < G_; off <<= 1) {
        int v = 0;
        if (t < G_) { v = s[t]; if (t >= off) v += s[t - off]; }
        __syncthreads();
        if (t < G_) s[t] = v;
        __syncthreads();
    }
    if (t < G_) gcur_n[b * G_ + t] = s[t] - gv;
}

__global__ __launch_bounds__(256) void k_fill_all(
    const int* __restrict__ recv, const int* __restrict__ egi,
    const int* __restrict__ ngi,
    int* __restrict__ cur, int* __restrict__ elist,
    int* __restrict__ gcur_e, int* __restrict__ gelist_e,
    int* __restrict__ gcur_n, int* __restrict__ gelist_n) {
    const int i = blockIdx.x * 256 + threadIdx.x;
    const int b = i >> 14;
    const int s1 = atomicAdd(&cur[b * N_ + recv[i]], 1);
    elist[b * E_ + s1] = i;
    const int s2 = atomicAdd(&gcur_e[b * G_ + egi[i]], 1);
    gelist_e[b * E_ + s2] = i;
    if (i < BN_) {
        const int b2 = i >> 12;
        const int s3 = atomicAdd(&gcur_n[b2 * G_ + ngi[i]], 1);
        gelist_n[b2 * N_ + s3] = i;
    }
}

// -------- edge GEMM: B staged in LDS (2-phase dbuf), A reg-gathered --------
// block: 128 rows x 64 cols (ch half), 4 waves x 32 rows. K = 4 segs of 128.
__global__ __launch_bounds__(256) void edge_mfma(
    const float* __restrict__ edges, const u16* __restrict__ nodesB,
    const u16* __restrict__ globB,
    const int* __restrict__ receivers, const int* __restrict__ senders,
    const int* __restrict__ egi,
    const u16* __restrict__ WeT, const float* __restrict__ be,
    float* __restrict__ uE) {
    __shared__ u16 Bs[2][64 * 128];            // 2 x 16KB
    const int tid = threadIdx.x;
    const int bid = blockIdx.x;                // 2048
    const int bb = bid & 7;                    // batch = XCD
    const int j = bid >> 3;                    // 0..255
    const int ch = j & 1;
    const int rt = j >> 1;                     // 0..127
    const int row0 = bb * E_ + rt * 128;

    const int wv = tid >> 6, l = tid & 63;
    const int fr = l & 15, fg = l >> 4;
    const int rowbase = row0 + wv * 32;
    const int R0 = rowbase + fr, R1 = R0 + 16;

    // B staging role: 4 chunks of 16B per thread per seg
    const char* wbase = (const char*)(WeT + (long)(ch * 64) * 512);
    int snl[4], sir[4], sdst[4];
    #pragma unroll
    for (int i = 0; i < 4; ++i) {
        const int c = tid + i * 256;           // 0..1023
        snl[i] = c >> 4;                       // B row (n_local)
        sir[i] = (c & 15) * 16;                // in-seg byte 0..255
        sdst[i] = snl[i] * 256 + (sir[i] ^ ((snl[i] & 7) << 4));
    }

    // A pointers
    const float* pE0 = edges + (long)R0 * DD;
    const float* pE1 = edges + (long)R1 * DD;
    const u16* nb = nodesB + (long)bb * (N_ * DD);
    const u16* pS0 = nb + (long)senders[R0] * DD;
    const u16* pS1 = nb + (long)senders[R1] * DD;
    const u16* pR0 = nb + (long)receivers[R0] * DD;
    const u16* pR1 = nb + (long)receivers[R1] * DD;
    const u16* pG0 = globB + ((long)bb * G_ + egi[R0]) * DD;
    const u16* pG1 = globB + ((long)bb * G_ + egi[R1]) * DD;

    // hoist seg0 A (edges, fp32 -> bf16): loads in flight during B staging
    short8 A0[4], A1[4];
    #pragma unroll
    for (int ss = 0; ss < 4; ++ss) {
        const int off = ss * 32 + fg * 8;
        A0[ss] = pack8(*(const float4*)(pE0 + off), *(const float4*)(pE0 + off + 4));
        A1[ss] = pack8(*(const float4*)(pE1 + off), *(const float4*)(pE1 + off + 4));
    }

    // prologue: stage seg0 B into Bs[0]
    #pragma unroll
    for (int i = 0; i < 4; ++i)
        *(short8*)((char*)Bs[0] + sdst[i]) =
            *(const short8*)(wbase + (long)snl[i] * 1024 + sir[i]);

    f32x4 acc0[4], acc1[4];
    const f32x4 fz = {0.f, 0.f, 0.f, 0.f};
    #pragma unroll
    for (int i = 0; i < 4; ++i) { acc0[i] = fz; acc1[i] = fz; }

    #pragma unroll
    for (int seg = 0; seg < 4; ++seg) {
        __syncthreads();
        // A loads for segs 1..3 (bf16 direct)
        if (seg > 0) {
            const u16* q0 = (seg == 1) ? pS0 : (seg == 2) ? pR0 : pG0;
            const u16* q1 = (seg == 1) ? pS1 : (seg == 2) ? pR1 : pG1;
            #pragma unroll
            for (int ss = 0; ss < 4; ++ss) {
                A0[ss] = *(const short8*)(q0 + ss * 32 + fg * 8);
                A1[ss] = *(const short8*)(q1 + ss * 32 + fg * 8);
            }
        }
        // stage next B seg into regs (latency hidden under MFMA below)
        short8 st[4];
        if (seg < 3) {
            #pragma unroll
            for (int i = 0; i < 4; ++i)
                st[i] = *(const short8*)(wbase + (long)snl[i] * 1024 +
                                         (seg + 1) * 256 + sir[i]);
        }
        // compute from Bs[seg&1]
        const char* bsp = (const char*)Bs[seg & 1];
        #pragma unroll
        for (int ss = 0; ss < 4; ++ss) {
            short8 bfr[4];
            #pragma unroll
            for (int nt = 0; nt < 4; ++nt) {
                int addr = ((nt * 16 + fr) << 8) + ss * 64 + fg * 16;
                addr ^= (fr & 7) << 4;
                bfr[nt] = *(const short8*)(bsp + addr);
            }
            #pragma unroll
            for (int nt = 0; nt < 4; ++nt) {
                acc0[nt] = __builtin_amdgcn_mfma_f32_16x16x32_bf16(A0[ss], bfr[nt], acc0[nt], 0, 0, 0);
                acc1[nt] = __builtin_amdgcn_mfma_f32_16x16x32_bf16(A1[ss], bfr[nt], acc1[nt], 0, 0, 0);
            }
        }
        // write staged B seg to the other buffer
        if (seg < 3) {
            #pragma unroll
            for (int i = 0; i < 4; ++i)
                *(short8*)((char*)Bs[(seg + 1) & 1] + sdst[i]) = st[i];
        }
    }

    #pragma unroll
    for (int nt = 0; nt < 4; ++nt) {
        const int c = ch * 64 + nt * 16 + fr;
        const float bias = be[c];
        #pragma unroll
        for (int r = 0; r < 4; ++r) {
            const int rr = rowbase + fg * 4 + r;
            uE[(long)rr * DD + c] = fmaxf(acc0[nt][r] + bias, 0.f);
            uE[(long)(rr + 16) * DD + c] = fmaxf(acc1[nt][r] + bias, 0.f);
        }
    }
}

// -------- adj = CSR gather-sum of u_e rows, written as bf16 --------
__global__ __launch_bounds__(256) void adj_gather(
    const int* __restrict__ cur, const int* __restrict__ cnt,
    const int* __restrict__ elist, const float* __restrict__ uE,
    u16* __restrict__ adjB) {
    const int tid = threadIdx.x;
    const int row = blockIdx.x * 64 + (tid >> 2);
    const int q = tid & 3;
    const int bb = row >> 12;
    const int deg = cnt[row];
    const int start = cur[row] - deg;
    const int* lp = elist + (long)bb * E_ + start;
    float4 a[8];
    #pragma unroll
    for (int j = 0; j < 8; ++j) a[j] = {0.f, 0.f, 0.f, 0.f};
    for (int i = 0; i < deg; ++i) {
        const float* up = uE + (long)lp[i] * DD + q * 32;
        #pragma unroll
        for (int j = 0; j < 8; ++j) {
            const float4 v = *(const float4*)(up + j * 4);
            a[j].x += v.x; a[j].y += v.y; a[j].z += v.z; a[j].w += v.w;
        }
    }
    u16* dst = adjB + (long)row * DD + q * 32;
    #pragma unroll
    for (int j = 0; j < 4; ++j)
        *(short8*)(dst + j * 8) = pack8(a[2 * j], a[2 * j + 1]);
}

// -------- node GEMM: same 2-phase LDS-B structure, K = 3 segs of 128 ------
__global__ __launch_bounds__(256) void node_mfma(
    const u16* __restrict__ nodesB, const u16* __restrict__ adjB,
    const u16* __restrict__ globB, const int* __restrict__ ngi,
    const u16* __restrict__ WnT, const float* __restrict__ bn,
    float* __restrict__ uN) {
    __shared__ u16 Bs[2][64 * 128];            // 2 x 16KB
    const int tid = threadIdx.x;
    const int bid = blockIdx.x;                // 512
    const int bb = bid & 7;
    const int j = bid >> 3;                    // 0..63
    const int ch = j & 1;
    const int rt = j >> 1;                     // 0..31
    const int row0 = bb * N_ + rt * 128;

    const int wv = tid >> 6, l = tid & 63;
    const int fr = l & 15, fg = l >> 4;
    const int rowbase = row0 + wv * 32;
    const int R0 = rowbase + fr, R1 = R0 + 16;

    const char* wbase = (const char*)(WnT + (long)(ch * 64) * 384);
    int snl[4], sir[4], sdst[4];
    #pragma unroll
    for (int i = 0; i < 4; ++i) {
        const int c = tid + i * 256;
        snl[i] = c >> 4;
        sir[i] = (c & 15) * 16;
        sdst[i] = snl[i] * 256 + (sir[i] ^ ((snl[i] & 7) << 4));
    }

    const u16* pN0 = nodesB + (long)R0 * DD;
    const u16* pN1 = nodesB + (long)R1 * DD;
    const u16* pA0 = adjB + (long)R0 * DD;
    const u16* pA1 = adjB + (long)R1 * DD;
    const u16* pG0 = globB + ((long)bb * G_ + ngi[R0]) * DD;
    const u16* pG1 = globB + ((long)bb * G_ + ngi[R1]) * DD;

    short8 A0[4], A1[4];
    #pragma unroll
    for (int ss = 0; ss < 4; ++ss) {
        A0[ss] = *(const short8*)(pN0 + ss * 32 + fg * 8);
        A1[ss] = *(const short8*)(pN1 + ss * 32 + fg * 8);
    }
    #pragma unroll
    for (int i = 0; i < 4; ++i)
        *(short8*)((char*)Bs[0] + sdst[i]) =
            *(const short8*)(wbase + (long)snl[i] * 768 + sir[i]);

    f32x4 acc0[4], acc1[4];
    const f32x4 fz = {0.f, 0.f, 0.f, 0.f};
    #pragma unroll
    for (int i = 0; i < 4; ++i) { acc0[i] = fz; acc1[i] = fz; }

    #pragma unroll
    for (int seg = 0; seg < 3; ++seg) {
        __syncthreads();
        if (seg > 0) {
            const u16* q0 = (seg == 1) ? pA0 : pG0;
            const u16* q1 = (seg == 1) ? pA1 : pG1;
            #pragma unroll
            for (int ss = 0; ss < 4; ++ss) {
                A0[ss] = *(const short8*)(q0 + ss * 32 + fg * 8);
                A1[ss] = *(const short8*)(q1 + ss * 32 + fg * 8);
            }
        }
        short8 st[4];
        if (seg < 2) {
            #pragma unroll
            for (int i = 0; i < 4; ++i)
                st[i] = *(const short8*)(wbase + (long)snl[i] * 768 +
                                         (seg + 1) * 256 + sir[i]);
        }
        const char* bsp = (const char*)Bs[seg & 1];
        #pragma unroll
        for (int ss = 0; ss < 4; ++ss) {
            short8 bfr[4];
            #pragma unroll
            for (int nt = 0; nt < 4; ++nt) {
                int addr = ((nt * 16 + fr) << 8) + ss * 64 + fg * 16;
                addr ^= (fr & 7) << 4;
                bfr[nt] = *(const short8*)(bsp + addr);
            }
            #pragma unroll
            for (int nt = 0; nt < 4; ++nt) {
                acc0[nt] = __builtin_amdgcn_mfma_f32_16x16x32_bf16(A0[ss], bfr[nt], acc0[nt], 0, 0, 0);
                acc1[nt] = __builtin_amdgcn_mfma_f32_16x16x32_bf16(A1[ss], bfr[nt], acc1[nt], 0, 0, 0);
            }
        }
        if (seg < 2) {
            #pragma unroll
            for (int i = 0; i < 4; ++i)
                *(short8*)((char*)Bs[(seg + 1) & 1] + sdst[i]) = st[i];
        }
    }

    #pragma unroll
    for (int nt = 0; nt < 4; ++nt) {
        const int c = ch * 64 + nt * 16 + fr;
        const float bias = bn[c];
        #pragma unroll
        for (int r = 0; r < 4; ++r) {
            const int rr = rowbase + fg * 4 + r;
            uN[(long)rr * DD + c] = fmaxf(acc0[nt][r] + bias, 0.f);
            uN[(long)(rr + 16) * DD + c] = fmaxf(acc1[nt][r] + bias, 0.f);
        }
    }
}

// -------- aggregate + fused residual, PART-way split --------
__global__ __launch_bounds__(256) void agg_resid(
    const int* __restrict__ gcnt, const int* __restrict__ gcur,
    const int* __restrict__ gelist, int spb,
    const float* __restrict__ xin, const float* __restrict__ w_res,
    float* __restrict__ u /* in-place -> x_out */,
    float* __restrict__ aggp /* [PART][BG][DD] */) {
    __shared__ float accl[1024];
    const int bg = blockIdx.x >> 2;
    const int p  = blockIdx.x & 3;
    const int b = bg >> 6;
    const int tid = threadIdx.x;
    const int c4 = (tid & 31) << 2;
    const int sub = tid >> 5;
    const int m = gcnt[bg];
    const int* lp = gelist + (long)b * spb + (gcur[bg] - m);
    const float wr = w_res[0];
    f32x4 acc = {0.f, 0.f, 0.f, 0.f};
    for (int j = p * 8 + sub; j < m; j += 32) {
        const long re = (long)lp[j] * DD + c4;
        const float4 v = *(const float4*)(u + re);
        const float4 x = *(const float4*)(xin + re);
        acc[0] += v.x; acc[1] += v.y; acc[2] += v.z; acc[3] += v.w;
        float4 o;
        o.x = x.x + wr * v.x; o.y = x.y + wr * v.y;
        o.z = x.z + wr * v.z; o.w = x.w + wr * v.w;
        *(float4*)(u + re) = o;
    }
    *(f32x4*)&accl[sub * 128 + c4] = acc;
    __syncthreads();
    if (tid < 128) {
        float s = 0.f;
        #pragma unroll
        for (int q = 0; q < 8; ++q) s += accl[q * 128 + tid];
        aggp[((long)p * BG_ + bg) * DD + tid] = s;
    }
}

// ---------------- global block: 512 rows, K=384, fp32 VALU ----------------
__global__ __launch_bounds__(128) void global_block(
    const float* __restrict__ naggp, const float* __restrict__ eaggp,
    const float* __restrict__ glob,
    const float* __restrict__ Wg, const float* __restrict__ bgb,
    const float* __restrict__ w_res, float* __restrict__ out) {
    __shared__ float gin[384];
    const int row = blockIdx.x;
    const int tid = threadIdx.x;
    float sn = 0.f, se = 0.f;
    #pragma unroll
    for (int p = 0; p < PART; ++p) {
        sn += naggp[((long)p * BG_ + row) * DD + tid];
        se += eaggp[((long)p * BG_ + row) * DD + tid];
    }
    gin[tid]       = sn;
    gin[128 + tid] = se;
    gin[256 + tid] = glob[row * DD + tid];
    __syncthreads();
    float acc = bgb[tid];
    #pragma unroll 4
    for (int k = 0; k < 384; ++k) acc += gin[k] * Wg[k * DD + tid];
    const float upd = fmaxf(acc, 0.f);
    out[OFF_GLOB + row * DD + tid] = glob[row * DD + tid] + w_res[0] * upd;
}

extern "C" void kernel_launch(void* const* d_in, const int* in_sizes, int n_in,
                              void* d_out, int out_size, void* d_ws, size_t ws_size,
                              hipStream_t stream) {
    const float* nodes     = (const float*)d_in[0];
    const float* edges     = (const float*)d_in[1];
    const int*   receivers = (const int*)d_in[2];
    const int*   senders   = (const int*)d_in[3];
    const float* glob      = (const float*)d_in[4];
    const int*   ngi       = (const int*)d_in[5];
    const int*   egi       = (const int*)d_in[6];
    const float* We        = (const float*)d_in[7];
    const float* be        = (const float*)d_in[8];
    const float* Wn        = (const float*)d_in[9];
    const float* bn        = (const float*)d_in[10];
    const float* Wg        = (const float*)d_in[11];
    const float* bg        = (const float*)d_in[12];
    const float* w_res     = (const float*)d_in[13];
    float* out = (float*)d_out;
    float* ws  = (float*)d_ws;

    float* eaggp = ws + WS_EAGGP;
    float* naggp = ws + WS_NAGGP;
    int* cnt      = (int*)(ws + WS_CNT);
    int* gcnt_e   = (int*)(ws + WS_GCNTE);
    int* gcnt_n   = (int*)(ws + WS_GCNTN);
    int* cur      = (int*)(ws + WS_CUR);
    int* gcur_e   = (int*)(ws + WS_GCURE);
    int* gcur_n   = (int*)(ws + WS_GCURN);
    int* elist    = (int*)(ws + WS_ELIST);
    int* gelist_e = (int*)(ws + WS_GELE);
    int* gelist_n = (int*)(ws + WS_GELN);
    u16* adjB   = (u16*)(ws + WS_ADJB);
    u16* nodesB = (u16*)(ws + WS_NODB);
    u16* globB  = (u16*)(ws + WS_GLOBB);
    u16* WeT    = (u16*)(ws + WS_WET);
    u16* WnT    = (u16*)(ws + WS_WNT);

    float* uE = out + OFF_EDGES;   // u_e, becomes edges_out after agg_resid
    float* uN = out + OFF_NODES;   // u_n, becomes nodes_out after agg_resid

    hipLaunchKernelGGL(prep_w, dim3(448), dim3(256), 0, stream, We, Wn, WeT, WnT);
    hipLaunchKernelGGL(cast_bf16, dim3(2080), dim3(256), 0, stream,
                       nodes, glob, nodesB, globB);
    hipLaunchKernelGGL(init_misc, dim3(1796), dim3(256), 0, stream,
                       receivers, senders, ngi, egi, out, cnt);
    hipLaunchKernelGGL(k_hist_all, dim3(512), dim3(256), 0, stream,
                       receivers, egi, ngi, cnt, gcnt_e, gcnt_n);
    hipLaunchKernelGGL(k_scan, dim3(8), dim3(1024), 0, stream,
                       cnt, cur, gcnt_e, gcur_e, gcnt_n, gcur_n);
    hipLaunchKernelGGL(k_fill_all, dim3(512), dim3(256), 0, stream,
                       receivers, egi, ngi, cur, elist, gcur_e, gelist_e,
                       gcur_n, gelist_n);
    hipLaunchKernelGGL(edge_mfma, dim3(2048), dim3(256), 0, stream,
                       edges, nodesB, globB, receivers, senders, egi, WeT, be, uE);
    hipLaunchKernelGGL(adj_gather, dim3(BN_ / 64), dim3(256), 0, stream,
                       cur, cnt, elist, uE, adjB);
    hipLaunchKernelGGL(agg_resid, dim3(BG_ * PART), dim3(256), 0, stream,
                       gcnt_e, gcur_e, gelist_e, E_, edges, w_res, uE, eaggp);
    hipLaunchKernelGGL(node_mfma, dim3(512), dim3(256), 0, stream,
                       nodesB, adjB, globB, ngi, WnT, bn, uN);
    hipLaunchKernelGGL(agg_resid, dim3(BG_ * PART), dim3(256), 0, stream,
                       gcnt_n, gcur_n, gelist_n, N_, nodes, w_res, uN, naggp);
    hipLaunchKernelGGL(global_block, dim3(BG_), dim3(128), 0, stream,
                       naggp, eaggp, glob, Wg, bg, w_res, out);
}